// Round 18
// baseline (67.170 us; speedup 1.0000x reference)
//
#include <hip/hip_runtime.h>
#include <hip/hip_bf16.h>
#include <stdint.h>

#define NPG 28
#define KDIM 896
#define NOUT 256
#define BM 128
#define BK 32
#define KT (KDIM / BK)   // 28

typedef __attribute__((ext_vector_type(8))) __bf16 bf16x8;
typedef __attribute__((ext_vector_type(8))) ushort us8;
typedef __attribute__((ext_vector_type(4))) float f32x4;

__device__ __forceinline__ ushort f2bf(float v) {
    uint u = __float_as_uint(v);
    return (ushort)((u + 0x7fffu + ((u >> 16) & 1u)) >> 16);
}

__device__ __forceinline__ void gload_lds16(const void* g, void* l) {
    __builtin_amdgcn_global_load_lds(
        (const __attribute__((address_space(1))) void*)(uintptr_t)g,
        (__attribute__((address_space(3))) void*)(uintptr_t)l,
        16, 0, 0);
}

// ---------------- k_agg: popc all-pairs scan, 512 threads / 16 graphs per block ----------------
// acc2g TRANSPOSED [j][graph]; Wt PHASE-TILED [kt][256][32] bf16.
// 16 graphs/block -> transposed-write segments grow 64B -> 128B (BW lever), blocks halve.
// pk/sx are GROUP-LOCAL (32-lane group within one wave) -> wave-local lgkmcnt(0) ordering.
__global__ __launch_bounds__(512) void k_agg(
    const float* __restrict__ x, const int* __restrict__ dst,
    const float* __restrict__ f1w,
    float* __restrict__ acc2g, ushort* __restrict__ wt, int nAgg)
{
    __shared__ int   pk[16][32];
    __shared__ float sx[16][32][2];
    __shared__ float t[32][33];

    const int tid = threadIdx.x;

    if ((int)blockIdx.x >= nAgg) {    // fc1_w transpose tiles (cross-wave -> keep barrier)
        int b = blockIdx.x - nAgg;
        int n0 = (b & 7) * 32, k0 = (b >> 3) * 32;
        int tx = tid & 31, ty = tid >> 5;            // ty 0..15
#pragma unroll
        for (int q = 0; q < 2; ++q)
            t[ty + q * 16][tx] = f1w[(k0 + ty + q * 16) * NOUT + n0 + tx];
        __syncthreads();
#pragma unroll
        for (int q = 0; q < 2; ++q)
            wt[(long)(k0 >> 5) * (NOUT * BK) + (n0 + ty + q * 16) * BK + tx] =
                f2bf(t[tx][ty + q * 16]);
        return;
    }

    const int g = tid >> 5;                          // group 0..15
    const int j = tid & 31;
    const long gb = ((long)blockIdx.x * 16 + g) * NPG;

    float2 xx = make_float2(0.f, 0.f);
    if (j < NPG) {
        int4 d4 = ((const int4*)dst)[gb + j];
        xx = ((const float2*)x)[gb + j];
        int gbi = (int)gb;
        pk[g][j] = (d4.x - gbi) | ((d4.y - gbi) << 8) |
                   ((d4.z - gbi) << 16) | ((d4.w - gbi) << 24);
    }
    asm volatile("s_waitcnt lgkmcnt(0)" ::: "memory");  // pk visible to this wave's groups

    const uint repj = (uint)j * 0x01010101u;
    uint cp0 = 0, cp1 = 0, cp2 = 0, cp3 = 0;
    int cnt = 0;
#pragma unroll
    for (int s4 = 0; s4 < 7; ++s4) {
        int4 pv = *(const int4*)&pk[g][s4 * 4];
#pragma unroll
        for (int r = 0; r < 4; ++r) {
            uint v = ((const uint*)&pv)[r] ^ repj;
            uint zb = ~(((v & 0x7F7F7F7Fu) + 0x7F7F7F7Fu) | v) & 0x80808080u;
            uint c = (uint)__popc(zb);
            cnt += (int)c;
            int s = s4 * 4 + r;
            uint nib = c << ((s & 7) * 4);
            if (s < 8)       cp0 |= nib;
            else if (s < 16) cp1 |= nib;
            else if (s < 24) cp2 |= nib;
            else             cp3 |= nib;
        }
    }

    const float dinv = rsqrtf((float)(1 + cnt));
    const float sx0 = xx.x * dinv, sx1 = xx.y * dinv;
    if (j < NPG) {
        sx[g][j][0] = sx0;
        sx[g][j][1] = sx1;
    }
    asm volatile("s_waitcnt lgkmcnt(0)" ::: "memory");  // sx visible to this wave's groups

    float a0 = sx0, a1 = sx1;
#pragma unroll
    for (int s = 0; s < NPG; ++s) {
        float2 sv = *(const float2*)&sx[g][s][0];
        uint cpw = (s < 8) ? cp0 : (s < 16) ? cp1 : (s < 24) ? cp2 : cp3;
        float cf = (float)((cpw >> ((s & 7) * 4)) & 0xFu);
        a0 += cf * sv.x;
        a1 += cf * sv.y;
    }

    if (j < NPG) {
        const long Btot = (long)nAgg * 16;
        const long graph = (long)blockIdx.x * 16 + g;
        ((float2*)acc2g)[(long)j * Btot + graph] = make_float2(a0 * dinv, a1 * dinv);
    }
}

// ---------------- k_gemm helpers (BM=128, 8 waves 2Mx4N, wave-tile 64x64) ----------------
// (byte-identical to round 13/17 — best verified GEMM: 50.0 µs)
__device__ __forceinline__ void stage_b2(const char* WtB, ushort* BsX, int kt, int tid) {
    const int o = (tid & 3) ^ ((tid >> 3) & 3);
    const long tb = (long)kt * 16384 + (tid >> 2) * 64 + o * 16;
    gload_lds16(WtB + tb,        (char*)BsX + tid * 16);
    gload_lds16(WtB + tb + 8192, (char*)BsX + 8192 + tid * 16);
}

__device__ __forceinline__ void agen_write(ushort* AsX, float2 av, int awoff,
                                           const float* w0, const float* w1, const float* bb) {
    union { us8 v; uint u[4]; } pk;
#pragma unroll
    for (int k = 0; k < 4; ++k) {
        float e0 = fmaxf(av.x * w0[2 * k]     + av.y * w1[2 * k]     + bb[2 * k],     0.f);
        float e1 = fmaxf(av.x * w0[2 * k + 1] + av.y * w1[2 * k + 1] + bb[2 * k + 1], 0.f);
        __hip_bfloat162 h = __float22bfloat162_rn(make_float2(e0, e1));
        pk.u[k] = *reinterpret_cast<uint*>(&h);
    }
    *(us8*)&AsX[awoff] = pk.v;
}

__device__ __forceinline__ void compute_mfma(const ushort* AsX, const ushort* BsX,
                                             f32x4 acc[4][4], int a_off, int b_off) {
    bf16x8 bfr[4];
#pragma unroll
    for (int ni = 0; ni < 4; ++ni)
        bfr[ni] = *(const bf16x8*)(&BsX[b_off + ni * 512]);
    __builtin_amdgcn_s_setprio(1);
#pragma unroll
    for (int mi = 0; mi < 4; ++mi) {
        bf16x8 af = *(const bf16x8*)(&AsX[a_off + mi * 512]);
#pragma unroll
        for (int ni = 0; ni < 4; ++ni)
            acc[mi][ni] = __builtin_amdgcn_mfma_f32_16x16x32_bf16(
                af, bfr[ni], acc[mi][ni], 0, 0, 0);
    }
    __builtin_amdgcn_s_setprio(0);
}

// ---------------- k_gemm: triple-Bs counted pipeline @ 128-unified regs (2 blocks/CU) ----------------
__global__ __launch_bounds__(512, 4) void k_gemm(
    const float* __restrict__ acc2g, const ushort* __restrict__ Wt,
    const float* __restrict__ cw, const float* __restrict__ cb,
    const float* __restrict__ f1b, const float* __restrict__ f2w,
    const float* __restrict__ f2b, float* __restrict__ out, int Bsz)
{
    __shared__ ushort As0[BM * BK], As1[BM * BK];               // 2 x 8KB
    __shared__ ushort Bs0[NOUT * BK], Bs1[NOUT * BK], Bs2[NOUT * BK]; // 3 x 16KB
    __shared__ float2 Aring[2][8][64];                          // 8KB -> total 72KB

    const int tid = threadIdx.x;
    const int w = tid >> 6, l = tid & 63;
    const int wM = w >> 2, wN = w & 3;
    const int l15 = l & 15, lhi = (l >> 4) & 3;
    const long m0 = (long)blockIdx.x * BM;
    const long BszB = (long)Bsz * 8;                 // bytes per A k-slice (transposed)

    const int ao = __builtin_amdgcn_readfirstlane(w & 3);
    const int arow = (w >> 2) * 64 + l;
    const int awoff = arow * 32 + ((ao ^ ((l >> 1) & 3)) * 8);
    float w0[8], w1[8], bb[8];
#pragma unroll
    for (int k = 0; k < 8; ++k) {
        w0[k] = cw[ao * 8 + k]; w1[k] = cw[32 + ao * 8 + k]; bb[k] = cb[ao * 8 + k];
    }

    const int swz = (lhi ^ ((l15 >> 1) & 3)) * 8;
    const int a_off = (wM * 64 + l15) * 32 + swz;    // + mi*512
    const int b_off = (wN * 64 + l15) * 32 + swz;    // + ni*512

    const char* A2B = (const char*)acc2g;            // transposed [kt][graph] f32x2
    const char* WtB = (const char*)Wt;               // phase-tiled [kt][256][32]
    const long agbase = (m0 + (long)(w >> 2) * 64 + 2 * l) * 8;

    f32x4 acc[4][4];
#pragma unroll
    for (int mi = 0; mi < 4; ++mi)
#pragma unroll
        for (int ni = 0; ni < 4; ++ni) acc[mi][ni] = (f32x4){0.f, 0.f, 0.f, 0.f};

    // ---- prologue: stage {Bs(0),A(0)}, {Bs(1),A(1)}; wait own first triple; publish ----
    stage_b2(WtB, Bs0, 0, tid);
    if (l < 32) gload_lds16(A2B + agbase,        (char*)&Aring[0][w][0]);
    stage_b2(WtB, Bs1, 1, tid);
    if (l < 32) gload_lds16(A2B + BszB + agbase, (char*)&Aring[1][w][0]);
    asm volatile("s_waitcnt vmcnt(3)" ::: "memory");
    __builtin_amdgcn_s_barrier();
    agen_write(As0, Aring[0][w][l], awoff, w0, w1, bb);
    asm volatile("s_waitcnt lgkmcnt(0)" ::: "memory");
    __builtin_amdgcn_s_barrier();

#define PH(BC, BS, AC, AN, RR, RS, KS) do {                                    \
        stage_b2(WtB, BS, (KS), tid);                                          \
        if (l < 32) gload_lds16(A2B + (long)(KS) * BszB + agbase,              \
                                (char*)&Aring[RS][w][0]);                      \
        compute_mfma(AC, BC, acc, a_off, b_off);                               \
        asm volatile("s_waitcnt vmcnt(3)" ::: "memory");                       \
        agen_write(AN, Aring[RR][w][l], awoff, w0, w1, bb);                    \
        asm volatile("s_waitcnt lgkmcnt(0)" ::: "memory");                     \
        __builtin_amdgcn_s_barrier();                                          \
    } while (0)

    for (int kt = 0; kt < 24; kt += 6) {
        PH(Bs0, Bs2, As0, As1, 1, 0, kt + 2);
        PH(Bs1, Bs0, As1, As0, 0, 1, kt + 3);
        PH(Bs2, Bs1, As0, As1, 1, 0, kt + 4);
        PH(Bs0, Bs2, As1, As0, 0, 1, kt + 5);
        PH(Bs1, Bs0, As0, As1, 1, 0, kt + 6);
        PH(Bs2, Bs1, As1, As0, 0, 1, kt + 7);
    }
    PH(Bs0, Bs2, As0, As1, 1, 0, 26);
    PH(Bs1, Bs0, As1, As0, 0, 1, 27);
    {   // phase 26
        compute_mfma(As0, Bs2, acc, a_off, b_off);
        asm volatile("s_waitcnt vmcnt(0)" ::: "memory");
        agen_write(As1, Aring[1][w][l], awoff, w0, w1, bb);
        asm volatile("s_waitcnt lgkmcnt(0)" ::: "memory");
        __builtin_amdgcn_s_barrier();
    }
    {   // phase 27
        compute_mfma(As1, Bs0, acc, a_off, b_off);
        asm volatile("s_waitcnt lgkmcnt(0)" ::: "memory");
        __builtin_amdgcn_s_barrier();
    }
#undef PH

    // ---- fused epilogue: +bias, row L2-norm, FC2, sigmoid/softplus ----
    float b1[4], w20[4], w21[4];
#pragma unroll
    for (int ni = 0; ni < 4; ++ni) {
        int col = wN * 64 + ni * 16 + l15;
        b1[ni] = f1b[col];
        w20[ni] = f2w[col * 2 + 0];
        w21[ni] = f2w[col * 2 + 1];
    }
    float* red    = (float*)As0;
    float* red_ss = red;             // [128][4]
    float* red_p0 = red + 512;
    float* red_p1 = red + 1024;
    float* red_rn = red + 1536;      // [128]

#pragma unroll
    for (int mi = 0; mi < 4; ++mi) {
        float ssr[4], p0r[4], p1r[4];
#pragma unroll
        for (int r = 0; r < 4; ++r) { ssr[r] = 0.f; p0r[r] = 0.f; p1r[r] = 0.f; }
#pragma unroll
        for (int ni = 0; ni < 4; ++ni) {
#pragma unroll
            for (int r = 0; r < 4; ++r) {
                float v = acc[mi][ni][r] + b1[ni];
                acc[mi][ni][r] = v;
                ssr[r] += v * v;
                p0r[r] += v * w20[ni];
                p1r[r] += v * w21[ni];
            }
        }
#pragma unroll
        for (int m = 1; m < 16; m <<= 1) {
#pragma unroll
            for (int r = 0; r < 4; ++r) {
                ssr[r] += __shfl_xor(ssr[r], m);
                p0r[r] += __shfl_xor(p0r[r], m);
                p1r[r] += __shfl_xor(p1r[r], m);
            }
        }
        if (l15 == 0) {
            int rowb = wM * 64 + mi * 16 + lhi * 4;
#pragma unroll
            for (int r = 0; r < 4; ++r) {
                red_ss[(rowb + r) * 4 + wN] = ssr[r];
                red_p0[(rowb + r) * 4 + wN] = p0r[r];
                red_p1[(rowb + r) * 4 + wN] = p1r[r];
            }
        }
    }
    __syncthreads();

    if (tid < BM) {
        int row = tid;
        float ss = red_ss[row * 4 + 0] + red_ss[row * 4 + 1] + red_ss[row * 4 + 2] + red_ss[row * 4 + 3];
        float p0 = red_p0[row * 4 + 0] + red_p0[row * 4 + 1] + red_p0[row * 4 + 2] + red_p0[row * 4 + 3];
        float p1 = red_p1[row * 4 + 0] + red_p1[row * 4 + 1] + red_p1[row * 4 + 2] + red_p1[row * 4 + 3];
        float rn = 1.0f / fmaxf(sqrtf(ss), 1e-12f);
        float x0 = p0 * rn + f2b[0];
        float x1 = p1 * rn + f2b[1];
        float mu = 1.0f / (1.0f + expf(-x0));
        float th = (x1 > 0.f) ? (x1 + log1pf(expf(-x1))) : log1pf(expf(x1));
        long gr = m0 + row;
        out[(long)Bsz * NOUT + gr] = mu;
        out[(long)Bsz * NOUT + Bsz + gr] = th;
        red_rn[row] = rn;
    }
    __syncthreads();

#pragma unroll
    for (int mi = 0; mi < 4; ++mi) {
        float rn[4];
#pragma unroll
        for (int r = 0; r < 4; ++r) rn[r] = red_rn[wM * 64 + mi * 16 + lhi * 4 + r];
#pragma unroll
        for (int ni = 0; ni < 4; ++ni) {
#pragma unroll
            for (int r = 0; r < 4; ++r) {
                long row = m0 + wM * 64 + mi * 16 + lhi * 4 + r;
                out[row * NOUT + wN * 64 + ni * 16 + l15] = acc[mi][ni][r] * rn[r];
            }
        }
    }
}

extern "C" void kernel_launch(void* const* d_in, const int* in_sizes, int n_in,
                              void* d_out, int out_size, void* d_ws, size_t ws_size,
                              hipStream_t stream) {
    const float* x   = (const float*)d_in[0];
    const int*   ei  = (const int*)d_in[1];
    const float* cw  = (const float*)d_in[2];
    const float* cb  = (const float*)d_in[3];
    const float* f1w = (const float*)d_in[4];
    const float* f1b = (const float*)d_in[5];
    const float* f2w = (const float*)d_in[6];
    const float* f2b = (const float*)d_in[7];
    float* out = (float*)d_out;

    const int Nn  = in_sizes[0] / 2;       // nodes
    const int Bsz = Nn / NPG;              // graphs
    const int E   = in_sizes[1] / 2;       // edges
    const int* dst = ei + E;

    float*  acc2g = (float*)d_ws;                      // [NPG][Bsz] f32x2 (transposed)
    ushort* Wt    = (ushort*)(acc2g + (size_t)Nn * 2); // [28][256][32] bf16 (phase-tiled)

    const int nAgg = Bsz / 16;                         // 4096 (16 graphs per block)
    const int nTr  = (KDIM / 32) * (NOUT / 32);        // 224

    k_agg<<<nAgg + nTr, 512, 0, stream>>>(x, dst, f1w, acc2g, Wt, nAgg);
    k_gemm<<<Bsz / BM, 512, 0, stream>>>(acc2g, Wt, cw, cb, f1b, f2w, f2b, out, Bsz);
}

// Round 19
// 66.308 us; speedup vs baseline: 1.0130x; 1.0130x over previous
//
#include <hip/hip_runtime.h>
#include <hip/hip_bf16.h>
#include <stdint.h>

#define NPG 28
#define KDIM 896
#define NOUT 256
#define BM 128
#define BK 32
#define KT (KDIM / BK)   // 28

typedef __attribute__((ext_vector_type(8))) __bf16 bf16x8;
typedef __attribute__((ext_vector_type(8))) ushort us8;
typedef __attribute__((ext_vector_type(4))) float f32x4;

__device__ __forceinline__ ushort f2bf(float v) {
    uint u = __float_as_uint(v);
    return (ushort)((u + 0x7fffu + ((u >> 16) & 1u)) >> 16);
}

__device__ __forceinline__ void gload_lds16(const void* g, void* l) {
    __builtin_amdgcn_global_load_lds(
        (const __attribute__((address_space(1))) void*)(uintptr_t)g,
        (__attribute__((address_space(3))) void*)(uintptr_t)l,
        16, 0, 0);
}

// ---------------- k_agg: popc all-pairs scan (best-measured r17 configuration) ----------------
// acc2g TRANSPOSED [j][graph]; Wt PHASE-TILED [kt][256][32] bf16.
// pk/sx are GROUP-LOCAL (32-lane group within one wave) -> wave-local lgkmcnt(0) ordering.
// r18 A/B: 16-graph/512-thread variant was neutral-to-worse -> reverted to 8-graph/256-thread.
__global__ __launch_bounds__(256) void k_agg(
    const float* __restrict__ x, const int* __restrict__ dst,
    const float* __restrict__ f1w,
    float* __restrict__ acc2g, ushort* __restrict__ wt, int nAgg)
{
    __shared__ int   pk[8][32];
    __shared__ float sx[8][32][2];
    __shared__ float t[32][33];

    const int tid = threadIdx.x;

    if ((int)blockIdx.x >= nAgg) {    // fc1_w transpose tiles (cross-wave -> keep barrier)
        int b = blockIdx.x - nAgg;
        int n0 = (b & 7) * 32, k0 = (b >> 3) * 32;
        int tx = tid & 31, ty = tid >> 5;
#pragma unroll
        for (int q = 0; q < 4; ++q)
            t[ty + q * 8][tx] = f1w[(k0 + ty + q * 8) * NOUT + n0 + tx];
        __syncthreads();
#pragma unroll
        for (int q = 0; q < 4; ++q)
            wt[(long)(k0 >> 5) * (NOUT * BK) + (n0 + ty + q * 8) * BK + tx] =
                f2bf(t[tx][ty + q * 8]);
        return;
    }

    const int g = tid >> 5;
    const int j = tid & 31;
    const long gb = ((long)blockIdx.x * 8 + g) * NPG;

    float2 xx = make_float2(0.f, 0.f);
    if (j < NPG) {
        int4 d4 = ((const int4*)dst)[gb + j];
        xx = ((const float2*)x)[gb + j];
        int gbi = (int)gb;
        pk[g][j] = (d4.x - gbi) | ((d4.y - gbi) << 8) |
                   ((d4.z - gbi) << 16) | ((d4.w - gbi) << 24);
    }
    asm volatile("s_waitcnt lgkmcnt(0)" ::: "memory");  // pk visible to this wave's groups

    const uint repj = (uint)j * 0x01010101u;
    uint cp0 = 0, cp1 = 0, cp2 = 0, cp3 = 0;
    int cnt = 0;
#pragma unroll
    for (int s4 = 0; s4 < 7; ++s4) {
        int4 pv = *(const int4*)&pk[g][s4 * 4];
#pragma unroll
        for (int r = 0; r < 4; ++r) {
            uint v = ((const uint*)&pv)[r] ^ repj;
            uint zb = ~(((v & 0x7F7F7F7Fu) + 0x7F7F7F7Fu) | v) & 0x80808080u;
            uint c = (uint)__popc(zb);
            cnt += (int)c;
            int s = s4 * 4 + r;
            uint nib = c << ((s & 7) * 4);
            if (s < 8)       cp0 |= nib;
            else if (s < 16) cp1 |= nib;
            else if (s < 24) cp2 |= nib;
            else             cp3 |= nib;
        }
    }

    const float dinv = rsqrtf((float)(1 + cnt));
    const float sx0 = xx.x * dinv, sx1 = xx.y * dinv;
    if (j < NPG) {
        sx[g][j][0] = sx0;
        sx[g][j][1] = sx1;
    }
    asm volatile("s_waitcnt lgkmcnt(0)" ::: "memory");  // sx visible to this wave's groups

    float a0 = sx0, a1 = sx1;
#pragma unroll
    for (int s = 0; s < NPG; ++s) {
        float2 sv = *(const float2*)&sx[g][s][0];
        uint cpw = (s < 8) ? cp0 : (s < 16) ? cp1 : (s < 24) ? cp2 : cp3;
        float cf = (float)((cpw >> ((s & 7) * 4)) & 0xFu);
        a0 += cf * sv.x;
        a1 += cf * sv.y;
    }

    if (j < NPG) {
        const long Btot = (long)nAgg * 8;
        const long graph = (long)blockIdx.x * 8 + g;
        ((float2*)acc2g)[(long)j * Btot + graph] = make_float2(a0 * dinv, a1 * dinv);
    }
}

// ---------------- k_gemm helpers (BM=128, 8 waves 2Mx4N, wave-tile 64x64) ----------------
// (byte-identical to round 13/17 — best verified GEMM: 50.0 µs)
__device__ __forceinline__ void stage_b2(const char* WtB, ushort* BsX, int kt, int tid) {
    const int o = (tid & 3) ^ ((tid >> 3) & 3);
    const long tb = (long)kt * 16384 + (tid >> 2) * 64 + o * 16;
    gload_lds16(WtB + tb,        (char*)BsX + tid * 16);
    gload_lds16(WtB + tb + 8192, (char*)BsX + 8192 + tid * 16);
}

__device__ __forceinline__ void agen_write(ushort* AsX, float2 av, int awoff,
                                           const float* w0, const float* w1, const float* bb) {
    union { us8 v; uint u[4]; } pk;
#pragma unroll
    for (int k = 0; k < 4; ++k) {
        float e0 = fmaxf(av.x * w0[2 * k]     + av.y * w1[2 * k]     + bb[2 * k],     0.f);
        float e1 = fmaxf(av.x * w0[2 * k + 1] + av.y * w1[2 * k + 1] + bb[2 * k + 1], 0.f);
        __hip_bfloat162 h = __float22bfloat162_rn(make_float2(e0, e1));
        pk.u[k] = *reinterpret_cast<uint*>(&h);
    }
    *(us8*)&AsX[awoff] = pk.v;
}

__device__ __forceinline__ void compute_mfma(const ushort* AsX, const ushort* BsX,
                                             f32x4 acc[4][4], int a_off, int b_off) {
    bf16x8 bfr[4];
#pragma unroll
    for (int ni = 0; ni < 4; ++ni)
        bfr[ni] = *(const bf16x8*)(&BsX[b_off + ni * 512]);
    __builtin_amdgcn_s_setprio(1);
#pragma unroll
    for (int mi = 0; mi < 4; ++mi) {
        bf16x8 af = *(const bf16x8*)(&AsX[a_off + mi * 512]);
#pragma unroll
        for (int ni = 0; ni < 4; ++ni)
            acc[mi][ni] = __builtin_amdgcn_mfma_f32_16x16x32_bf16(
                af, bfr[ni], acc[mi][ni], 0, 0, 0);
    }
    __builtin_amdgcn_s_setprio(0);
}

// ---------------- k_gemm: triple-Bs counted pipeline @ 128-unified regs (2 blocks/CU) ----------------
__global__ __launch_bounds__(512, 4) void k_gemm(
    const float* __restrict__ acc2g, const ushort* __restrict__ Wt,
    const float* __restrict__ cw, const float* __restrict__ cb,
    const float* __restrict__ f1b, const float* __restrict__ f2w,
    const float* __restrict__ f2b, float* __restrict__ out, int Bsz)
{
    __shared__ ushort As0[BM * BK], As1[BM * BK];               // 2 x 8KB
    __shared__ ushort Bs0[NOUT * BK], Bs1[NOUT * BK], Bs2[NOUT * BK]; // 3 x 16KB
    __shared__ float2 Aring[2][8][64];                          // 8KB -> total 72KB

    const int tid = threadIdx.x;
    const int w = tid >> 6, l = tid & 63;
    const int wM = w >> 2, wN = w & 3;
    const int l15 = l & 15, lhi = (l >> 4) & 3;
    const long m0 = (long)blockIdx.x * BM;
    const long BszB = (long)Bsz * 8;                 // bytes per A k-slice (transposed)

    const int ao = __builtin_amdgcn_readfirstlane(w & 3);
    const int arow = (w >> 2) * 64 + l;
    const int awoff = arow * 32 + ((ao ^ ((l >> 1) & 3)) * 8);
    float w0[8], w1[8], bb[8];
#pragma unroll
    for (int k = 0; k < 8; ++k) {
        w0[k] = cw[ao * 8 + k]; w1[k] = cw[32 + ao * 8 + k]; bb[k] = cb[ao * 8 + k];
    }

    const int swz = (lhi ^ ((l15 >> 1) & 3)) * 8;
    const int a_off = (wM * 64 + l15) * 32 + swz;    // + mi*512
    const int b_off = (wN * 64 + l15) * 32 + swz;    // + ni*512

    const char* A2B = (const char*)acc2g;            // transposed [kt][graph] f32x2
    const char* WtB = (const char*)Wt;               // phase-tiled [kt][256][32]
    const long agbase = (m0 + (long)(w >> 2) * 64 + 2 * l) * 8;

    f32x4 acc[4][4];
#pragma unroll
    for (int mi = 0; mi < 4; ++mi)
#pragma unroll
        for (int ni = 0; ni < 4; ++ni) acc[mi][ni] = (f32x4){0.f, 0.f, 0.f, 0.f};

    // ---- prologue: stage {Bs(0),A(0)}, {Bs(1),A(1)}; wait own first triple; publish ----
    stage_b2(WtB, Bs0, 0, tid);
    if (l < 32) gload_lds16(A2B + agbase,        (char*)&Aring[0][w][0]);
    stage_b2(WtB, Bs1, 1, tid);
    if (l < 32) gload_lds16(A2B + BszB + agbase, (char*)&Aring[1][w][0]);
    asm volatile("s_waitcnt vmcnt(3)" ::: "memory");
    __builtin_amdgcn_s_barrier();
    agen_write(As0, Aring[0][w][l], awoff, w0, w1, bb);
    asm volatile("s_waitcnt lgkmcnt(0)" ::: "memory");
    __builtin_amdgcn_s_barrier();

#define PH(BC, BS, AC, AN, RR, RS, KS) do {                                    \
        stage_b2(WtB, BS, (KS), tid);                                          \
        if (l < 32) gload_lds16(A2B + (long)(KS) * BszB + agbase,              \
                                (char*)&Aring[RS][w][0]);                      \
        compute_mfma(AC, BC, acc, a_off, b_off);                               \
        asm volatile("s_waitcnt vmcnt(3)" ::: "memory");                       \
        agen_write(AN, Aring[RR][w][l], awoff, w0, w1, bb);                    \
        asm volatile("s_waitcnt lgkmcnt(0)" ::: "memory");                     \
        __builtin_amdgcn_s_barrier();                                          \
    } while (0)

    for (int kt = 0; kt < 24; kt += 6) {
        PH(Bs0, Bs2, As0, As1, 1, 0, kt + 2);
        PH(Bs1, Bs0, As1, As0, 0, 1, kt + 3);
        PH(Bs2, Bs1, As0, As1, 1, 0, kt + 4);
        PH(Bs0, Bs2, As1, As0, 0, 1, kt + 5);
        PH(Bs1, Bs0, As0, As1, 1, 0, kt + 6);
        PH(Bs2, Bs1, As1, As0, 0, 1, kt + 7);
    }
    PH(Bs0, Bs2, As0, As1, 1, 0, 26);
    PH(Bs1, Bs0, As1, As0, 0, 1, 27);
    {   // phase 26
        compute_mfma(As0, Bs2, acc, a_off, b_off);
        asm volatile("s_waitcnt vmcnt(0)" ::: "memory");
        agen_write(As1, Aring[1][w][l], awoff, w0, w1, bb);
        asm volatile("s_waitcnt lgkmcnt(0)" ::: "memory");
        __builtin_amdgcn_s_barrier();
    }
    {   // phase 27
        compute_mfma(As1, Bs0, acc, a_off, b_off);
        asm volatile("s_waitcnt lgkmcnt(0)" ::: "memory");
        __builtin_amdgcn_s_barrier();
    }
#undef PH

    // ---- fused epilogue: +bias, row L2-norm, FC2, sigmoid/softplus ----
    float b1[4], w20[4], w21[4];
#pragma unroll
    for (int ni = 0; ni < 4; ++ni) {
        int col = wN * 64 + ni * 16 + l15;
        b1[ni] = f1b[col];
        w20[ni] = f2w[col * 2 + 0];
        w21[ni] = f2w[col * 2 + 1];
    }
    float* red    = (float*)As0;
    float* red_ss = red;             // [128][4]
    float* red_p0 = red + 512;
    float* red_p1 = red + 1024;
    float* red_rn = red + 1536;      // [128]

#pragma unroll
    for (int mi = 0; mi < 4; ++mi) {
        float ssr[4], p0r[4], p1r[4];
#pragma unroll
        for (int r = 0; r < 4; ++r) { ssr[r] = 0.f; p0r[r] = 0.f; p1r[r] = 0.f; }
#pragma unroll
        for (int ni = 0; ni < 4; ++ni) {
#pragma unroll
            for (int r = 0; r < 4; ++r) {
                float v = acc[mi][ni][r] + b1[ni];
                acc[mi][ni][r] = v;
                ssr[r] += v * v;
                p0r[r] += v * w20[ni];
                p1r[r] += v * w21[ni];
            }
        }
#pragma unroll
        for (int m = 1; m < 16; m <<= 1) {
#pragma unroll
            for (int r = 0; r < 4; ++r) {
                ssr[r] += __shfl_xor(ssr[r], m);
                p0r[r] += __shfl_xor(p0r[r], m);
                p1r[r] += __shfl_xor(p1r[r], m);
            }
        }
        if (l15 == 0) {
            int rowb = wM * 64 + mi * 16 + lhi * 4;
#pragma unroll
            for (int r = 0; r < 4; ++r) {
                red_ss[(rowb + r) * 4 + wN] = ssr[r];
                red_p0[(rowb + r) * 4 + wN] = p0r[r];
                red_p1[(rowb + r) * 4 + wN] = p1r[r];
            }
        }
    }
    __syncthreads();

    if (tid < BM) {
        int row = tid;
        float ss = red_ss[row * 4 + 0] + red_ss[row * 4 + 1] + red_ss[row * 4 + 2] + red_ss[row * 4 + 3];
        float p0 = red_p0[row * 4 + 0] + red_p0[row * 4 + 1] + red_p0[row * 4 + 2] + red_p0[row * 4 + 3];
        float p1 = red_p1[row * 4 + 0] + red_p1[row * 4 + 1] + red_p1[row * 4 + 2] + red_p1[row * 4 + 3];
        float rn = 1.0f / fmaxf(sqrtf(ss), 1e-12f);
        float x0 = p0 * rn + f2b[0];
        float x1 = p1 * rn + f2b[1];
        float mu = 1.0f / (1.0f + expf(-x0));
        float th = (x1 > 0.f) ? (x1 + log1pf(expf(-x1))) : log1pf(expf(x1));
        long gr = m0 + row;
        out[(long)Bsz * NOUT + gr] = mu;
        out[(long)Bsz * NOUT + Bsz + gr] = th;
        red_rn[row] = rn;
    }
    __syncthreads();

#pragma unroll
    for (int mi = 0; mi < 4; ++mi) {
        float rn[4];
#pragma unroll
        for (int r = 0; r < 4; ++r) rn[r] = red_rn[wM * 64 + mi * 16 + lhi * 4 + r];
#pragma unroll
        for (int ni = 0; ni < 4; ++ni) {
#pragma unroll
            for (int r = 0; r < 4; ++r) {
                long row = m0 + wM * 64 + mi * 16 + lhi * 4 + r;
                out[row * NOUT + wN * 64 + ni * 16 + l15] = acc[mi][ni][r] * rn[r];
            }
        }
    }
}

extern "C" void kernel_launch(void* const* d_in, const int* in_sizes, int n_in,
                              void* d_out, int out_size, void* d_ws, size_t ws_size,
                              hipStream_t stream) {
    const float* x   = (const float*)d_in[0];
    const int*   ei  = (const int*)d_in[1];
    const float* cw  = (const float*)d_in[2];
    const float* cb  = (const float*)d_in[3];
    const float* f1w = (const float*)d_in[4];
    const float* f1b = (const float*)d_in[5];
    const float* f2w = (const float*)d_in[6];
    const float* f2b = (const float*)d_in[7];
    float* out = (float*)d_out;

    const int Nn  = in_sizes[0] / 2;       // nodes
    const int Bsz = Nn / NPG;              // graphs
    const int E   = in_sizes[1] / 2;       // edges
    const int* dst = ei + E;

    float*  acc2g = (float*)d_ws;                      // [NPG][Bsz] f32x2 (transposed)
    ushort* Wt    = (ushort*)(acc2g + (size_t)Nn * 2); // [28][256][32] bf16 (phase-tiled)

    const int nAgg = Bsz / 8;                          // 8192 (8 graphs per block)
    const int nTr  = (KDIM / 32) * (NOUT / 32);        // 224

    k_agg<<<nAgg + nTr, 256, 0, stream>>>(x, dst, f1w, acc2g, Wt, nAgg);
    k_gemm<<<Bsz / BM, 512, 0, stream>>>(acc2g, Wt, cw, cb, f1b, f2w, f2b, out, Bsz);
}